// Round 1
// baseline (36564.481 us; speedup 1.0000x reference)
//
#include <hip/hip_runtime.h>

// LSTM_65859028517106 — round 1: wavefront pipeline, one kernel per global step.
// bf16 MFMA (16x16x32), gate-interleaved weight rows (row' = 4*unit + gate) so
// each lane's 4 acc regs = (i,f,g,o) of one unit -> cell update is lane-local.

typedef short s16x8 __attribute__((ext_vector_type(8)));
typedef float f32x4 __attribute__((ext_vector_type(4)));

#define NB   128   // batch
#define TT   1024  // timesteps
#define HID2 512

__device__ __forceinline__ unsigned short f2bf(float f) {
  union { float f; unsigned int u; } c; c.f = f;
  return (unsigned short)((c.u + 0x7fffu + ((c.u >> 16) & 1u)) >> 16);
}
__device__ __forceinline__ float sigm(float x) { return 1.0f / (1.0f + __expf(-x)); }
__device__ __forceinline__ float tanhfast(float x) {
  x = fminf(fmaxf(x, -15.0f), 15.0f);
  const float e = __expf(2.0f * x);
  return (e - 1.0f) / (e + 1.0f);
}

// Build combined bf16 weight matrix W'[2048][Kih+Khh], rows interleaved 4u+g,
// cols = [Wih | Whh]; also combined bias.
__global__ void convW(const float* __restrict__ Wih, const float* __restrict__ Whh,
                      const float* __restrict__ bih, const float* __restrict__ bhh,
                      unsigned short* __restrict__ Wd, float* __restrict__ biasd,
                      const int Kih, const int Khh) {
  const int K = Kih + Khh;
  const int total = 2048 * K;
  for (int idx = blockIdx.x * blockDim.x + threadIdx.x; idx < total;
       idx += gridDim.x * blockDim.x) {
    const int rp = idx / K;
    const int cc = idx - rp * K;
    const int g = rp & 3, u = rp >> 2;
    const int ro = g * 512 + u;
    const float v = (cc < Kih) ? Wih[ro * Kih + cc] : Whh[ro * Khh + (cc - Kih)];
    Wd[idx] = f2bf(v);
    if (cc == 0) biasd[rp] = bih[ro] + bhh[ro];
  }
}

__global__ void convO(const float* __restrict__ Wout, unsigned short* __restrict__ Wd) {
  for (int idx = blockIdx.x * blockDim.x + threadIdx.x; idx < 128 * 512;
       idx += gridDim.x * blockDim.x)
    Wd[idx] = f2bf(Wout[idx]);
}

// One wavefront step. blocks 0..159: layer l = bid>>5 computes t = s-l.
// blocks 160..167: output projection of h5 at t = s-5.
__global__ __launch_bounds__(256) void lstm_step(
    const int s,
    const float* __restrict__ x,
    const unsigned short* __restrict__ W0, const unsigned short* __restrict__ W1,
    const unsigned short* __restrict__ W2, const unsigned short* __restrict__ W3,
    const unsigned short* __restrict__ W4,
    const unsigned short* __restrict__ Woutb,
    const float* __restrict__ bias,
    unsigned short* __restrict__ hbuf,   // [5][2][128][512] bf16
    float* __restrict__ cbuf,            // [5][512][128] f32
    const float* __restrict__ boutp,
    float* __restrict__ outp)            // [128][1024][128] f32
{
  __shared__ __align__(16) char smem[16384];  // 2 x 8KB Bs double buffer
  const int tid = threadIdx.x;
  const int lane = tid & 63;
  const int w = tid >> 6;       // wave 0..3
  const int l15 = lane & 15;
  const int l4 = lane >> 4;     // 0..3
  const int bid = blockIdx.x;

  if (bid < 160) {
    const int l = bid >> 5;
    const int wgi = bid & 31;
    const int t = s - l;
    if (t < 0 || t >= TT) return;
    const int K = (l == 0) ? 640 : 1024;
    const unsigned short* W = (l == 0) ? W0 : (l == 1) ? W1 : (l == 2) ? W2 : (l == 3) ? W3 : W4;
    const int row0 = wgi * 64;
    const int slotP = t & 1, slotM = (t - 1) & 1;
    const unsigned short* hih =
        hbuf + (size_t)((l > 0 ? (l - 1) * 2 + slotP : 0)) * (NB * HID2);
    const unsigned short* hhh = hbuf + (size_t)(l * 2 + slotM) * (NB * HID2);

    f32x4 acc[4][2] = {};

    // Stage Bs tile for k-iter 'kit' into 'buf': layout [kc(4)][b(128)] 16B chunks,
    // chunk c holds h_cat[b = c&127][k0 + (c>>7)*8 .. +8).
    auto stageBs = [&](int kit, char* buf) {
      const int k0 = kit << 5;
      if (l == 0 && k0 < 128) {
        // x slice: fp32 -> bf16 register staging
        #pragma unroll
        for (int j = 0; j < 2; ++j) {
          const int cch = 256 * j + tid;
          const int bS = cch & 127, kcS = cch >> 7;
          const int kg = k0 + kcS * 8;
          const float* xs = x + ((size_t)bS * TT + t) * 128 + kg;
          const float4 v0 = *(const float4*)xs;
          const float4 v1 = *(const float4*)(xs + 4);
          union { s16x8 v; unsigned short a[8]; } pk;
          pk.a[0] = f2bf(v0.x); pk.a[1] = f2bf(v0.y); pk.a[2] = f2bf(v0.z); pk.a[3] = f2bf(v0.w);
          pk.a[4] = f2bf(v1.x); pk.a[5] = f2bf(v1.y); pk.a[6] = f2bf(v1.z); pk.a[7] = f2bf(v1.w);
          *reinterpret_cast<s16x8*>(buf + cch * 16) = pk.v;
        }
      } else {
        #pragma unroll
        for (int j = 0; j < 2; ++j) {
          const int cch = 256 * j + tid;
          const int bS = cch & 127, kcS = cch >> 7;
          const int kg = k0 + kcS * 8;
          const unsigned short* src;
          if (l == 0)           src = hhh + (size_t)bS * HID2 + (kg - 128);
          else if (kg < HID2)   src = hih + (size_t)bS * HID2 + kg;
          else                  src = hhh + (size_t)bS * HID2 + (kg - HID2);
          __builtin_amdgcn_global_load_lds(
              (const __attribute__((address_space(1))) unsigned int*)(const void*)src,
              (__attribute__((address_space(3))) unsigned int*)(void*)(buf + (256 * j + 64 * w) * 16),
              16, 0, 0);
        }
      }
    };
    auto loadA = [&](s16x8* dst, int kit) {
      const int k0 = kit << 5;
      #pragma unroll
      for (int mf = 0; mf < 4; ++mf)
        dst[mf] = *reinterpret_cast<const s16x8*>(
            W + (size_t)(row0 + mf * 16 + l15) * K + k0 + l4 * 8);
    };

    const int nit = K >> 5;
    s16x8 a[4], an[4];
    stageBs(0, smem);
    loadA(a, 0);
    __syncthreads();
    for (int kit = 0; kit < nit; ++kit) {
      char* cur = smem + (kit & 1) * 8192;
      char* nxt = smem + ((kit + 1) & 1) * 8192;
      if (kit + 1 < nit) { stageBs(kit + 1, nxt); loadA(an, kit + 1); }
      #pragma unroll
      for (int nf = 0; nf < 2; ++nf) {
        const s16x8 b = *reinterpret_cast<const s16x8*>(
            cur + (l4 * 128 + w * 32 + nf * 16 + l15) * 16);
        #pragma unroll
        for (int mf = 0; mf < 4; ++mf)
          acc[mf][nf] = __builtin_amdgcn_mfma_f32_16x16x32_bf16(a[mf], b, acc[mf][nf], 0, 0, 0);
      }
      #pragma unroll
      for (int mf = 0; mf < 4; ++mf) a[mf] = an[mf];
      __syncthreads();
    }

    // Epilogue: lane holds gates (i,f,g,o) of unit u for batch b in acc regs 0..3.
    unsigned short* hout = hbuf + (size_t)(l * 2 + slotP) * (NB * HID2);
    float* cl = cbuf + (size_t)l * (HID2 * NB);
    #pragma unroll
    for (int mf = 0; mf < 4; ++mf) {
      const float4 b4 = *(const float4*)(bias + l * 2048 + row0 + mf * 16 + l4 * 4);
      const int u = wgi * 16 + mf * 4 + l4;
      #pragma unroll
      for (int nf = 0; nf < 2; ++nf) {
        const int b = w * 32 + nf * 16 + l15;
        const float gi = acc[mf][nf][0] + b4.x;
        const float gf = acc[mf][nf][1] + b4.y;
        const float gg = acc[mf][nf][2] + b4.z;
        const float go = acc[mf][nf][3] + b4.w;
        const float cold = cl[u * NB + b];
        const float cn = sigm(gf) * cold + sigm(gi) * tanhfast(gg);
        const float hn = sigm(go) * tanhfast(cn);
        cl[u * NB + b] = cn;
        hout[(size_t)b * HID2 + u] = f2bf(hn);
      }
    }
  } else {
    // ---- projection: out[b][tp][:] = h5[tp] @ Wout^T + bout
    const int wgp = bid - 160;
    const int tp = s - 5;
    if (tp < 0) return;
    const int b0 = wgp * 16;
    const unsigned short* h4 = hbuf + (size_t)(4 * 2 + (tp & 1)) * (NB * HID2);
    f32x4 acc2[2] = {};
    #pragma unroll 4
    for (int kit = 0; kit < 16; ++kit) {
      const int k = kit * 32 + l4 * 8;
      const s16x8 bfr = *reinterpret_cast<const s16x8*>(h4 + (size_t)(b0 + l15) * HID2 + k);
      #pragma unroll
      for (int mf = 0; mf < 2; ++mf) {
        const s16x8 afr = *reinterpret_cast<const s16x8*>(
            Woutb + (size_t)(w * 32 + mf * 16 + l15) * HID2 + k);
        acc2[mf] = __builtin_amdgcn_mfma_f32_16x16x32_bf16(afr, bfr, acc2[mf], 0, 0, 0);
      }
    }
    #pragma unroll
    for (int mf = 0; mf < 2; ++mf) {
      const int d0 = w * 32 + mf * 16 + l4 * 4;
      const int b = b0 + l15;
      const float4 bo = *(const float4*)(boutp + d0);
      float4 r;
      r.x = acc2[mf][0] + bo.x;
      r.y = acc2[mf][1] + bo.y;
      r.z = acc2[mf][2] + bo.z;
      r.w = acc2[mf][3] + bo.w;
      *(float4*)(outp + ((size_t)b * TT + tp) * 128 + d0) = r;
    }
  }
}

extern "C" void kernel_launch(void* const* d_in, const int* in_sizes, int n_in,
                              void* d_out, int out_size, void* d_ws, size_t ws_size,
                              hipStream_t stream) {
  (void)in_sizes; (void)n_in; (void)out_size; (void)ws_size;
  const float* x     = (const float*)d_in[0];
  const float* Wih1  = (const float*)d_in[1];
  const float* Whh1  = (const float*)d_in[2];
  const float* bih1  = (const float*)d_in[3];
  const float* bhh1  = (const float*)d_in[4];
  const float* Wih_r = (const float*)d_in[5];
  const float* Whh_r = (const float*)d_in[6];
  const float* bih_r = (const float*)d_in[7];
  const float* bhh_r = (const float*)d_in[8];
  const float* Wout  = (const float*)d_in[9];
  const float* boutp = (const float*)d_in[10];
  // d_in[11] = future, always 0 in this problem.

  char* ws = (char*)d_ws;
  const size_t o_W0   = 0;
  const size_t o_W1   = o_W0 + 2048ull * 640 * 2;
  const size_t o_W2   = o_W1 + 2048ull * 1024 * 2;
  const size_t o_W3   = o_W2 + 2048ull * 1024 * 2;
  const size_t o_W4   = o_W3 + 2048ull * 1024 * 2;
  const size_t o_Wout = o_W4 + 2048ull * 1024 * 2;
  const size_t o_bias = o_Wout + 128ull * 512 * 2;
  const size_t o_h    = o_bias + 5ull * 2048 * 4;
  const size_t o_c    = o_h + 5ull * 2 * NB * HID2 * 2;
  const size_t o_end  = o_c + 5ull * HID2 * NB * 4;

  unsigned short* W0b  = (unsigned short*)(ws + o_W0);
  unsigned short* W1b  = (unsigned short*)(ws + o_W1);
  unsigned short* W2b  = (unsigned short*)(ws + o_W2);
  unsigned short* W3b  = (unsigned short*)(ws + o_W3);
  unsigned short* W4b  = (unsigned short*)(ws + o_W4);
  unsigned short* Wob  = (unsigned short*)(ws + o_Wout);
  float*          bias = (float*)(ws + o_bias);
  unsigned short* hbuf = (unsigned short*)(ws + o_h);
  float*          cbuf = (float*)(ws + o_c);

  // zero h ping-pong buffers + c state (initial states are zeros)
  hipMemsetAsync(ws + o_h, 0, o_end - o_h, stream);

  convW<<<1024, 256, 0, stream>>>(Wih1, Whh1, bih1, bhh1, W0b, bias, 128, 512);
  for (int l = 1; l <= 4; ++l) {
    unsigned short* Wd = (l == 1) ? W1b : (l == 2) ? W2b : (l == 3) ? W3b : W4b;
    convW<<<1024, 256, 0, stream>>>(Wih_r + (size_t)(l - 1) * 2048 * 512,
                                    Whh_r + (size_t)(l - 1) * 2048 * 512,
                                    bih_r + (size_t)(l - 1) * 2048,
                                    bhh_r + (size_t)(l - 1) * 2048,
                                    Wd, bias + l * 2048, 512, 512);
  }
  convO<<<64, 256, 0, stream>>>(Wout, Wob);

  for (int s = 0; s < 1029; ++s)
    lstm_step<<<168, 256, 0, stream>>>(s, x, W0b, W1b, W2b, W3b, W4b, Wob, bias,
                                       hbuf, cbuf, boutp, (float*)d_out);
}

// Round 2
// 31406.738 us; speedup vs baseline: 1.1642x; 1.1642x over previous
//
#include <hip/hip_runtime.h>

// LSTM_65859028517106 — round 2: single persistent kernel, flag-synced
// producer/consumer pipeline. W as pre-arranged MFMA fragments in LDS
// (loaded once), c-state in registers, h in 8-deep global ring,
// wave-private B staging ring (depth 3) with counted vmcnt waits.

typedef short s16x8 __attribute__((ext_vector_type(8)));
typedef float f32x4 __attribute__((ext_vector_type(4)));

#define NB   128
#define TT   1024
#define HID2 512
#define RING 8
#define NBH  (NB * HID2)   // elems per h ring slot

__device__ __forceinline__ unsigned short f2bf(float f) {
  union { float f; unsigned int u; } c; c.f = f;
  return (unsigned short)((c.u + 0x7fffu + ((c.u >> 16) & 1u)) >> 16);
}
__device__ __forceinline__ float sigm(float x) { return 1.0f / (1.0f + __expf(-x)); }
__device__ __forceinline__ float tanhfast(float x) {
  x = fminf(fmaxf(x, -15.0f), 15.0f);
  const float e = __expf(2.0f * x);
  return (e - 1.0f) / (e + 1.0f);
}

// Build combined bf16 weight matrix W'[2048][Kih+Khh], rows interleaved 4u+g.
__global__ void convW(const float* __restrict__ Wih, const float* __restrict__ Whh,
                      const float* __restrict__ bih, const float* __restrict__ bhh,
                      unsigned short* __restrict__ Wd, float* __restrict__ biasd,
                      const int Kih, const int Khh) {
  const int K = Kih + Khh;
  const int total = 2048 * K;
  for (int idx = blockIdx.x * blockDim.x + threadIdx.x; idx < total;
       idx += gridDim.x * blockDim.x) {
    const int rp = idx / K;
    const int cc = idx - rp * K;
    const int g = rp & 3, u = rp >> 2;
    const int ro = g * 512 + u;
    const float v = (cc < Kih) ? Wih[ro * Kih + cc] : Whh[ro * Khh + (cc - Kih)];
    Wd[idx] = f2bf(v);
    if (cc == 0) biasd[rp] = bih[ro] + bhh[ro];
  }
}

__global__ void convO(const float* __restrict__ Wout, unsigned short* __restrict__ Wd) {
  for (int idx = blockIdx.x * blockDim.x + threadIdx.x; idx < 128 * 512;
       idx += gridDim.x * blockDim.x)
    Wd[idx] = f2bf(Wout[idx]);
}

// ---------------- persistent pipeline kernel ----------------
// blocks 0..159 : layer l = bid>>5, wgi = bid&31 (owns 64 gate rows = 16 units)
// blocks 160..167: output projection (16 batch rows each)
__global__ __launch_bounds__(256, 1) void lstm_persist(
    const float* __restrict__ x,
    const unsigned short* __restrict__ W0, const unsigned short* __restrict__ W1,
    const unsigned short* __restrict__ W2, const unsigned short* __restrict__ W3,
    const unsigned short* __restrict__ W4,
    const unsigned short* __restrict__ Woutb,
    const float* __restrict__ bias,
    unsigned short* __restrict__ hring,   // [5][RING][128][512] bf16
    unsigned int* __restrict__ cnt,       // [6][TT] produce counters (count to 32)
    const float* __restrict__ boutp,
    float* __restrict__ outp)             // [128][1024][128] f32
{
  extern __shared__ char smem[];
  const int tid = threadIdx.x;
  const int lane = tid & 63;
  const int w = tid >> 6;
  const int l15 = lane & 15;
  const int l4 = lane >> 4;
  const int bid = blockIdx.x;

  auto poll = [&](const unsigned int* p, unsigned int tgt) {
    while (__hip_atomic_load(p, __ATOMIC_RELAXED, __HIP_MEMORY_SCOPE_AGENT) < tgt)
      __builtin_amdgcn_s_sleep(1);
  };

  if (bid < 160) {
    const int l = bid >> 5;
    const int wgi = bid & 31;
    const int K = (l == 0) ? 640 : 1024;
    const int nkit = K >> 5;
    const int kitBeg = (l == 0) ? 4 : 0;  // layer 0: kits 0..3 come from x (regs)
    const unsigned short* Wg = (l == 0) ? W0 : (l == 1) ? W1 : (l == 2) ? W2
                              : (l == 3) ? W3 : W4;
    const int row0 = wgi * 64;

    // ---- one-time: preload W fragments into LDS, fragment-contiguous ----
    // frag (mf,kit) at smem + (mf*nkit+kit)*1024 + lane*16 holds
    // W[row0 + mf*16 + l15][kit*32 + l4*8 .. +8]  (matches r1 loadA, verified)
    for (int mf = 0; mf < 4; ++mf)
      for (int kit = w; kit < nkit; kit += 4) {
        const s16x8 v = *reinterpret_cast<const s16x8*>(
            Wg + (size_t)(row0 + mf * 16 + l15) * K + kit * 32 + l4 * 8);
        *reinterpret_cast<s16x8*>(smem + ((mf * nkit + kit) << 10) + lane * 16) = v;
      }
    char* ringB = smem + ((4 * nkit) << 10);  // 3 slots x 8 KB
    __syncthreads();

    float4 b4m[4];
    #pragma unroll
    for (int mf = 0; mf < 4; ++mf)
      b4m[mf] = *(const float4*)(bias + l * 2048 + row0 + mf * 16 + l4 * 4);

    float c_reg[4][2] = {};
    const int bl = lane & 31, kh = lane >> 5;
    unsigned int* cl_prev = (l > 0) ? cnt + (l - 1) * TT : nullptr;
    unsigned int* cl_self = cnt + l * TT;
    unsigned int* cl_next = cnt + (l + 1) * TT;

    for (int t = 0; t < TT; ++t) {
      const unsigned short* hin =
          (l > 0) ? hring + (size_t)((l - 1) * RING + (t & 7)) * NBH : nullptr;
      const unsigned short* hown = hring + (size_t)(l * RING + ((t + 7) & 7)) * NBH;
      unsigned short* hout = hring + (size_t)(l * RING + (t & 7)) * NBH;

      f32x4 acc[4][2] = {};

      auto srcFor = [&](int j, const unsigned short*& hb, int& kb) {
        if (l == 0)       { hb = hown; kb = j * 32 - 128; }
        else if (j < 16)  { hb = hin;  kb = j * 32; }
        else              { hb = hown; kb = j * 32 - 512; }
      };
      auto stage = [&](int j, int slot) {
        const unsigned short* hb; int kb; srcFor(j, hb, kb);
        char* db = ringB + slot * 8192 + w * 2048;
        #pragma unroll
        for (int i = 0; i < 2; ++i) {
          const unsigned short* src = hb + (size_t)(w * 32 + bl) * HID2 + kb + (i * 2 + kh) * 8;
          __builtin_amdgcn_global_load_lds(
              (const __attribute__((address_space(1))) unsigned int*)(const void*)src,
              (__attribute__((address_space(3))) unsigned int*)(void*)(db + i * 1024),
              16, 0, 0);
        }
      };

      if (l == 0) {
        // prefetch x fragments BEFORE the spins (x is flag-independent)
        s16x8 xb[4][2];
        #pragma unroll
        for (int kx = 0; kx < 4; ++kx)
          #pragma unroll
          for (int nf = 0; nf < 2; ++nf) {
            const float* xs = x + ((size_t)(w * 32 + nf * 16 + l15) * TT + t) * 128
                              + kx * 32 + l4 * 8;
            const float4 v0 = *(const float4*)xs;
            const float4 v1 = *(const float4*)(xs + 4);
            union { s16x8 v; unsigned short a[8]; } pk;
            pk.a[0] = f2bf(v0.x); pk.a[1] = f2bf(v0.y); pk.a[2] = f2bf(v0.z); pk.a[3] = f2bf(v0.w);
            pk.a[4] = f2bf(v1.x); pk.a[5] = f2bf(v1.y); pk.a[6] = f2bf(v1.z); pk.a[7] = f2bf(v1.w);
            xb[kx][nf] = pk.v;
          }
        if (t > 0)        poll(cl_self + (t - 1), 32u);
        if (t >= RING)    poll(cl_next + (t - RING), 32u);
        __builtin_amdgcn_fence(__ATOMIC_ACQUIRE, "agent");
        stage(4, 0); stage(5, 1);
        #pragma unroll
        for (int kx = 0; kx < 4; ++kx)
          #pragma unroll
          for (int mf = 0; mf < 4; ++mf) {
            const s16x8 af = *reinterpret_cast<const s16x8*>(
                smem + ((mf * 20 + kx) << 10) + lane * 16);
            acc[mf][0] = __builtin_amdgcn_mfma_f32_16x16x32_bf16(af, xb[kx][0], acc[mf][0], 0, 0, 0);
            acc[mf][1] = __builtin_amdgcn_mfma_f32_16x16x32_bf16(af, xb[kx][1], acc[mf][1], 0, 0, 0);
          }
      } else {
        poll(cl_prev + t, 32u);
        if (t > 0)        poll(cl_self + (t - 1), 32u);
        if (t >= RING)    poll(cl_next + (t - RING), 32u);
        __builtin_amdgcn_fence(__ATOMIC_ACQUIRE, "agent");
        stage(0, 0); stage(1, 1);
      }

      // ---- staged k-loop ----
      int cur = 0;
      for (int kit = kitBeg; kit < nkit; ++kit) {
        if (kit + 2 < nkit) {
          stage(kit + 2, cur == 0 ? 2 : cur - 1);
          asm volatile("s_waitcnt vmcnt(4)" ::: "memory");
        } else if (kit + 1 < nkit) {
          asm volatile("s_waitcnt vmcnt(2)" ::: "memory");
        } else {
          asm volatile("s_waitcnt vmcnt(0)" ::: "memory");
        }
        const char* rb = ringB + cur * 8192 + w * 2048;
        const s16x8 bf0 = *(const s16x8*)(rb + l4 * 512 + l15 * 16);
        const s16x8 bf1 = *(const s16x8*)(rb + l4 * 512 + (16 + l15) * 16);
        #pragma unroll
        for (int mf = 0; mf < 4; ++mf) {
          const s16x8 af = *reinterpret_cast<const s16x8*>(
              smem + ((mf * nkit + kit) << 10) + lane * 16);
          acc[mf][0] = __builtin_amdgcn_mfma_f32_16x16x32_bf16(af, bf0, acc[mf][0], 0, 0, 0);
          acc[mf][1] = __builtin_amdgcn_mfma_f32_16x16x32_bf16(af, bf1, acc[mf][1], 0, 0, 0);
        }
        cur = (cur == 2) ? 0 : cur + 1;
      }

      // ---- epilogue: gates -> c,h (c in regs), h -> ring ----
      #pragma unroll
      for (int mf = 0; mf < 4; ++mf) {
        const int u = wgi * 16 + mf * 4 + l4;
        #pragma unroll
        for (int nf = 0; nf < 2; ++nf) {
          const int b = w * 32 + nf * 16 + l15;
          const float gi = acc[mf][nf][0] + b4m[mf].x;
          const float gf = acc[mf][nf][1] + b4m[mf].y;
          const float gg = acc[mf][nf][2] + b4m[mf].z;
          const float go = acc[mf][nf][3] + b4m[mf].w;
          const float cn = sigm(gf) * c_reg[mf][nf] + sigm(gi) * tanhfast(gg);
          c_reg[mf][nf] = cn;
          hout[(size_t)b * HID2 + u] = f2bf(sigm(go) * tanhfast(cn));
        }
      }
      __builtin_amdgcn_fence(__ATOMIC_RELEASE, "agent");
      __syncthreads();
      if (tid == 0)
        __hip_atomic_fetch_add(cl_self + t, 1u, __ATOMIC_RELAXED, __HIP_MEMORY_SCOPE_AGENT);
    }
  } else {
    // ---------------- projection blocks ----------------
    const int wgp = bid - 160;
    const int b0 = wgp * 16;
    // preload Wout frags (wave-private): frag (w,mf,kit) holds
    // Woutb[(w*32+mf*16+l15)*512 + kit*32 + l4*8 .. +8]
    for (int mf = 0; mf < 2; ++mf)
      for (int kit = 0; kit < 16; ++kit) {
        const s16x8 v = *reinterpret_cast<const s16x8*>(
            Woutb + (size_t)(w * 32 + mf * 16 + l15) * 512 + kit * 32 + l4 * 8);
        *reinterpret_cast<s16x8*>(smem + (((w * 2 + mf) * 16 + kit) << 10) + lane * 16) = v;
      }
    __syncthreads();
    float4 bo[2];
    #pragma unroll
    for (int mf = 0; mf < 2; ++mf)
      bo[mf] = *(const float4*)(boutp + w * 32 + mf * 16 + l4 * 4);

    unsigned int* cl4 = cnt + 4 * TT;
    unsigned int* cl5 = cnt + 5 * TT;
    for (int t = 0; t < TT; ++t) {
      poll(cl4 + t, 32u);
      __builtin_amdgcn_fence(__ATOMIC_ACQUIRE, "agent");
      const unsigned short* h4 = hring + (size_t)(4 * RING + (t & 7)) * NBH;
      f32x4 acc2[2] = {};
      #pragma unroll 4
      for (int kit = 0; kit < 16; ++kit) {
        const s16x8 bfr = *reinterpret_cast<const s16x8*>(
            h4 + (size_t)(b0 + l15) * HID2 + kit * 32 + l4 * 8);
        #pragma unroll
        for (int mf = 0; mf < 2; ++mf) {
          const s16x8 af = *reinterpret_cast<const s16x8*>(
              smem + (((w * 2 + mf) * 16 + kit) << 10) + lane * 16);
          acc2[mf] = __builtin_amdgcn_mfma_f32_16x16x32_bf16(af, bfr, acc2[mf], 0, 0, 0);
        }
      }
      #pragma unroll
      for (int mf = 0; mf < 2; ++mf) {
        const int d0 = w * 32 + mf * 16 + l4 * 4;
        float4 r;
        r.x = acc2[mf][0] + bo[mf].x;
        r.y = acc2[mf][1] + bo[mf].y;
        r.z = acc2[mf][2] + bo[mf].z;
        r.w = acc2[mf][3] + bo[mf].w;
        *(float4*)(outp + ((size_t)(b0 + l15) * TT + t) * 128 + d0) = r;
      }
      __builtin_amdgcn_fence(__ATOMIC_RELEASE, "agent");
      __syncthreads();
      if (tid == 0)
        __hip_atomic_fetch_add(cl5 + t, 4u, __ATOMIC_RELAXED, __HIP_MEMORY_SCOPE_AGENT);
    }
  }
}

extern "C" void kernel_launch(void* const* d_in, const int* in_sizes, int n_in,
                              void* d_out, int out_size, void* d_ws, size_t ws_size,
                              hipStream_t stream) {
  (void)in_sizes; (void)n_in; (void)out_size; (void)ws_size;
  const float* x     = (const float*)d_in[0];
  const float* Wih1  = (const float*)d_in[1];
  const float* Whh1  = (const float*)d_in[2];
  const float* bih1  = (const float*)d_in[3];
  const float* bhh1  = (const float*)d_in[4];
  const float* Wih_r = (const float*)d_in[5];
  const float* Whh_r = (const float*)d_in[6];
  const float* bih_r = (const float*)d_in[7];
  const float* bhh_r = (const float*)d_in[8];
  const float* Wout  = (const float*)d_in[9];
  const float* boutp = (const float*)d_in[10];

  char* ws = (char*)d_ws;
  const size_t o_W0   = 0;
  const size_t o_W1   = o_W0 + 2048ull * 640 * 2;
  const size_t o_W2   = o_W1 + 2048ull * 1024 * 2;
  const size_t o_W3   = o_W2 + 2048ull * 1024 * 2;
  const size_t o_W4   = o_W3 + 2048ull * 1024 * 2;
  const size_t o_Wout = o_W4 + 2048ull * 1024 * 2;
  const size_t o_bias = o_Wout + 128ull * 512 * 2;
  const size_t o_ring = o_bias + 5ull * 2048 * 4;
  const size_t o_cnt  = o_ring + 5ull * RING * NBH * 2;
  const size_t o_end  = o_cnt + 6ull * TT * 4;

  unsigned short* W0b  = (unsigned short*)(ws + o_W0);
  unsigned short* W1b  = (unsigned short*)(ws + o_W1);
  unsigned short* W2b  = (unsigned short*)(ws + o_W2);
  unsigned short* W3b  = (unsigned short*)(ws + o_W3);
  unsigned short* W4b  = (unsigned short*)(ws + o_W4);
  unsigned short* Wob  = (unsigned short*)(ws + o_Wout);
  float*          bias = (float*)(ws + o_bias);
  unsigned short* hrg  = (unsigned short*)(ws + o_ring);
  unsigned int*   cnt  = (unsigned int*)(ws + o_cnt);

  // zero h ring + counters every call (deterministic across graph replays)
  hipMemsetAsync(ws + o_ring, 0, o_end - o_ring, stream);

  convW<<<1024, 256, 0, stream>>>(Wih1, Whh1, bih1, bhh1, W0b, bias, 128, 512);
  for (int l = 1; l <= 4; ++l) {
    unsigned short* Wd = (l == 1) ? W1b : (l == 2) ? W2b : (l == 3) ? W3b : W4b;
    convW<<<1024, 256, 0, stream>>>(Wih_r + (size_t)(l - 1) * 2048 * 512,
                                    Whh_r + (size_t)(l - 1) * 2048 * 512,
                                    bih_r + (size_t)(l - 1) * 2048,
                                    bhh_r + (size_t)(l - 1) * 2048,
                                    Wd, bias + l * 2048, 512, 512);
  }
  convO<<<64, 256, 0, stream>>>(Wout, Wob);

  static bool attr_set = false;
  // (idempotent + deterministic; required for >64KB dynamic LDS)
  hipFuncSetAttribute((const void*)lstm_persist,
                      hipFuncAttributeMaxDynamicSharedMemorySize, 160 * 1024);
  (void)attr_set;

  lstm_persist<<<168, 256, 155648, stream>>>(x, W0b, W1b, W2b, W3b, W4b, Wob,
                                             bias, hrg, cnt, boutp, (float*)d_out);
}

// Round 3
// 13504.697 us; speedup vs baseline: 2.7075x; 2.3256x over previous
//
#include <hip/hip_runtime.h>

// LSTM_65859028517106 — round 3: persistent kernel, fence-free device coherence.
// h + flags via sc0/sc1 (L1/L2-bypass, Infinity-Cache-coherent) inline-asm ops;
// B fragments global->VGPR with 16-deep register ring + counted vmcnt waits
// ("+v" idiom ties MFMA operands to the waitcnt). No atomics, no cache fences.

typedef short s16x8 __attribute__((ext_vector_type(8)));
typedef float f32x4 __attribute__((ext_vector_type(4)));

#define NB   128
#define TT   1024
#define HID2 512
#define RING 8
#define NBH  (NB * HID2)

__device__ __forceinline__ unsigned short f2bf(float f) {
  union { float f; unsigned int u; } c; c.f = f;
  return (unsigned short)((c.u + 0x7fffu + ((c.u >> 16) & 1u)) >> 16);
}
__device__ __forceinline__ float sigm(float x) { return 1.0f / (1.0f + __expf(-x)); }
__device__ __forceinline__ float tanhfast(float x) {
  x = fminf(fmaxf(x, -15.0f), 15.0f);
  const float e = __expf(2.0f * x);
  return (e - 1.0f) / (e + 1.0f);
}

__global__ void convW(const float* __restrict__ Wih, const float* __restrict__ Whh,
                      const float* __restrict__ bih, const float* __restrict__ bhh,
                      unsigned short* __restrict__ Wd, float* __restrict__ biasd,
                      const int Kih, const int Khh) {
  const int K = Kih + Khh;
  const int total = 2048 * K;
  for (int idx = blockIdx.x * blockDim.x + threadIdx.x; idx < total;
       idx += gridDim.x * blockDim.x) {
    const int rp = idx / K;
    const int cc = idx - rp * K;
    const int g = rp & 3, u = rp >> 2;
    const int ro = g * 512 + u;
    const float v = (cc < Kih) ? Wih[ro * Kih + cc] : Whh[ro * Khh + (cc - Kih)];
    Wd[idx] = f2bf(v);
    if (cc == 0) biasd[rp] = bih[ro] + bhh[ro];
  }
}

__global__ void convO(const float* __restrict__ Wout, unsigned short* __restrict__ Wd) {
  for (int idx = blockIdx.x * blockDim.x + threadIdx.x; idx < 128 * 512;
       idx += gridDim.x * blockDim.x)
    Wd[idx] = f2bf(Wout[idx]);
}

// --- sc0/sc1 (device-coherent) asm helpers ---
#define GLD2(D0, D1, B0, B1, OFF)                                         \
  asm volatile("global_load_dwordx4 %0, %2, off offset:" OFF " sc0 sc1\n\t" \
               "global_load_dwordx4 %1, %3, off offset:" OFF " sc0 sc1"   \
               : "=v"(D0), "=v"(D1) : "v"(B0), "v"(B1));
#define BWAIT(D0, D1, VM)                                                 \
  asm volatile("s_waitcnt vmcnt(" VM ")" : "+v"(D0), "+v"(D1)::"memory");
#define GLD1(D, B, OFF)                                                   \
  asm volatile("global_load_dwordx4 %0, %1, off offset:" OFF " sc0 sc1"   \
               : "=v"(D) : "v"(B));
#define BW1(D, VM)                                                        \
  asm volatile("s_waitcnt vmcnt(" VM ")" : "+v"(D)::"memory");

#define MFM(A, B, C) __builtin_amdgcn_mfma_f32_16x16x32_bf16(A, B, C, 0, 0, 0)
#define LDSA(MFi, AK) \
  (*reinterpret_cast<const s16x8*>(smem + (((MFi) * nkit + (AK)) << 10) + lane * 16))
#define CONSUME(SLOT, AK, VM)                                                   \
  {                                                                             \
    BWAIT(bq[SLOT][0], bq[SLOT][1], VM);                                        \
    const s16x8 af0 = LDSA(0, AK), af1 = LDSA(1, AK), af2 = LDSA(2, AK),        \
                af3 = LDSA(3, AK);                                              \
    acc[0][0] = MFM(af0, bq[SLOT][0], acc[0][0]);                               \
    acc[0][1] = MFM(af0, bq[SLOT][1], acc[0][1]);                               \
    acc[1][0] = MFM(af1, bq[SLOT][0], acc[1][0]);                               \
    acc[1][1] = MFM(af1, bq[SLOT][1], acc[1][1]);                               \
    acc[2][0] = MFM(af2, bq[SLOT][0], acc[2][0]);                               \
    acc[2][1] = MFM(af2, bq[SLOT][1], acc[2][1]);                               \
    acc[3][0] = MFM(af3, bq[SLOT][0], acc[3][0]);                               \
    acc[3][1] = MFM(af3, bq[SLOT][1], acc[3][1]);                               \
  }

__global__ __launch_bounds__(256, 1) void lstm_persist(
    const float* __restrict__ x,
    const unsigned short* __restrict__ W0, const unsigned short* __restrict__ W1,
    const unsigned short* __restrict__ W2, const unsigned short* __restrict__ W3,
    const unsigned short* __restrict__ W4,
    const unsigned short* __restrict__ Woutb,
    const float* __restrict__ bias,
    unsigned short* __restrict__ hring,   // [5][RING][128][512] bf16 (sc1 domain)
    unsigned int* __restrict__ flags,     // [6][TT][32] u32 (sc1 domain)
    const float* __restrict__ boutp,
    float* __restrict__ outp)
{
  extern __shared__ char smem[];
  const int tid = threadIdx.x;
  const int lane = tid & 63;
  const int w = tid >> 6;
  const int l15 = lane & 15;
  const int l4 = lane >> 4;
  const int bid = blockIdx.x;

  auto pollAll = [&](const unsigned int* pa) {
    for (;;) {
      unsigned int v;
      asm volatile("global_load_dword %0, %1, off sc0 sc1\n\ts_waitcnt vmcnt(0)"
                   : "=v"(v) : "v"(pa) : "memory");
      if (__all(v != 0)) break;
      __builtin_amdgcn_s_sleep(1);
    }
  };
  #define FLG(L, T) (flags + ((size_t)((L) * TT + (T)) << 5))

  if (bid < 160) {
    const int l = bid >> 5;
    const int wgi = bid & 31;
    const int K = (l == 0) ? 640 : 1024;
    const int nkit = K >> 5;
    const unsigned short* Wg = (l == 0) ? W0 : (l == 1) ? W1 : (l == 2) ? W2
                              : (l == 3) ? W3 : W4;
    const int row0 = wgi * 64;

    // one-time W fragment preload into LDS (normal cached loads)
    for (int mf = 0; mf < 4; ++mf)
      for (int kit = w; kit < nkit; kit += 4) {
        const s16x8 v = *reinterpret_cast<const s16x8*>(
            Wg + (size_t)(row0 + mf * 16 + l15) * K + kit * 32 + l4 * 8);
        *reinterpret_cast<s16x8*>(smem + ((mf * nkit + kit) << 10) + lane * 16) = v;
      }
    __syncthreads();

    float4 b4m[4];
    #pragma unroll
    for (int mf = 0; mf < 4; ++mf)
      b4m[mf] = *(const float4*)(bias + l * 2048 + row0 + mf * 16 + l4 * 4);

    float c_reg[4][2] = {};
    s16x8 bq[16][2];

    for (int t = 0; t < TT; ++t) {
      const unsigned short* hin =
          (l > 0) ? hring + (size_t)((l - 1) * RING + (t & 7)) * NBH : nullptr;
      const unsigned short* hown = hring + (size_t)(l * RING + ((t + 7) & 7)) * NBH;
      unsigned short* hout = hring + (size_t)(l * RING + (t & 7)) * NBH;

      f32x4 acc[4][2] = {};
      s16x8 xb[4][2];

      if (l == 0) {
        // x prefetch + convert (flag-independent, cached)
        #pragma unroll
        for (int kx = 0; kx < 4; ++kx)
          #pragma unroll
          for (int nf = 0; nf < 2; ++nf) {
            const float* xs = x + ((size_t)(w * 32 + nf * 16 + l15) * TT + t) * 128
                              + kx * 32 + l4 * 8;
            const float4 v0 = *(const float4*)xs;
            const float4 v1 = *(const float4*)(xs + 4);
            union { s16x8 v; unsigned short a[8]; } pk;
            pk.a[0] = f2bf(v0.x); pk.a[1] = f2bf(v0.y); pk.a[2] = f2bf(v0.z); pk.a[3] = f2bf(v0.w);
            pk.a[4] = f2bf(v1.x); pk.a[5] = f2bf(v1.y); pk.a[6] = f2bf(v1.z); pk.a[7] = f2bf(v1.w);
            xb[kx][nf] = pk.v;
          }
      }

      // fused poll: lanes 0..31 = self(t-1), lanes 32..63 = prev(t)
      if (t > 0 || l > 0) {
        const unsigned int* pa;
        if (lane < 32)
          pa = (t > 0) ? FLG(l, t - 1) + lane : FLG(l - 1, t) + lane;
        else
          pa = (l > 0) ? FLG(l - 1, t) + (lane - 32) : FLG(l, t - 1) + (lane - 32);
        pollAll(pa);
      }

      const unsigned short* pb0 = hown + (size_t)(w * 32 + l15) * HID2 + l4 * 8;
      const unsigned short* pb1 = pb0 + 16 * HID2;

      if (l == 0) {
        // issue all 16 hown kits (abs kits 4..19)
        GLD2(bq[0][0], bq[0][1], pb0, pb1, "0")    GLD2(bq[1][0], bq[1][1], pb0, pb1, "64")
        GLD2(bq[2][0], bq[2][1], pb0, pb1, "128")  GLD2(bq[3][0], bq[3][1], pb0, pb1, "192")
        GLD2(bq[4][0], bq[4][1], pb0, pb1, "256")  GLD2(bq[5][0], bq[5][1], pb0, pb1, "320")
        GLD2(bq[6][0], bq[6][1], pb0, pb1, "384")  GLD2(bq[7][0], bq[7][1], pb0, pb1, "448")
        GLD2(bq[8][0], bq[8][1], pb0, pb1, "512")  GLD2(bq[9][0], bq[9][1], pb0, pb1, "576")
        GLD2(bq[10][0], bq[10][1], pb0, pb1, "640") GLD2(bq[11][0], bq[11][1], pb0, pb1, "704")
        GLD2(bq[12][0], bq[12][1], pb0, pb1, "768") GLD2(bq[13][0], bq[13][1], pb0, pb1, "832")
        GLD2(bq[14][0], bq[14][1], pb0, pb1, "896") GLD2(bq[15][0], bq[15][1], pb0, pb1, "960")
        // x MFMAs cover load latency (abs kits 0..3)
        #pragma unroll
        for (int kx = 0; kx < 4; ++kx) {
          const s16x8 a0 = LDSA(0, kx), a1 = LDSA(1, kx), a2 = LDSA(2, kx), a3 = LDSA(3, kx);
          acc[0][0] = MFM(a0, xb[kx][0], acc[0][0]); acc[0][1] = MFM(a0, xb[kx][1], acc[0][1]);
          acc[1][0] = MFM(a1, xb[kx][0], acc[1][0]); acc[1][1] = MFM(a1, xb[kx][1], acc[1][1]);
          acc[2][0] = MFM(a2, xb[kx][0], acc[2][0]); acc[2][1] = MFM(a2, xb[kx][1], acc[2][1]);
          acc[3][0] = MFM(a3, xb[kx][0], acc[3][0]); acc[3][1] = MFM(a3, xb[kx][1], acc[3][1]);
        }
        CONSUME(0, 4, "30")   CONSUME(1, 5, "28")   CONSUME(2, 6, "26")   CONSUME(3, 7, "24")
        CONSUME(4, 8, "22")   CONSUME(5, 9, "20")   CONSUME(6, 10, "18")  CONSUME(7, 11, "16")
        CONSUME(8, 12, "14")  CONSUME(9, 13, "12")  CONSUME(10, 14, "10") CONSUME(11, 15, "8")
        CONSUME(12, 16, "6")  CONSUME(13, 17, "4")  CONSUME(14, 18, "2")  CONSUME(15, 19, "0")
      } else {
        const unsigned short* qb0 = hin + (size_t)(w * 32 + l15) * HID2 + l4 * 8;
        const unsigned short* qb1 = qb0 + 16 * HID2;
        // issue 16 hown kits (abs 16..31)
        GLD2(bq[0][0], bq[0][1], pb0, pb1, "0")    GLD2(bq[1][0], bq[1][1], pb0, pb1, "64")
        GLD2(bq[2][0], bq[2][1], pb0, pb1, "128")  GLD2(bq[3][0], bq[3][1], pb0, pb1, "192")
        GLD2(bq[4][0], bq[4][1], pb0, pb1, "256")  GLD2(bq[5][0], bq[5][1], pb0, pb1, "320")
        GLD2(bq[6][0], bq[6][1], pb0, pb1, "384")  GLD2(bq[7][0], bq[7][1], pb0, pb1, "448")
        GLD2(bq[8][0], bq[8][1], pb0, pb1, "512")  GLD2(bq[9][0], bq[9][1], pb0, pb1, "576")
        GLD2(bq[10][0], bq[10][1], pb0, pb1, "640") GLD2(bq[11][0], bq[11][1], pb0, pb1, "704")
        GLD2(bq[12][0], bq[12][1], pb0, pb1, "768") GLD2(bq[13][0], bq[13][1], pb0, pb1, "832")
        GLD2(bq[14][0], bq[14][1], pb0, pb1, "896") GLD2(bq[15][0], bq[15][1], pb0, pb1, "960")
        // consume hown, reissue slot from hin (abs 0..15)
        CONSUME(0, 16, "30")  GLD2(bq[0][0], bq[0][1], qb0, qb1, "0")
        CONSUME(1, 17, "30")  GLD2(bq[1][0], bq[1][1], qb0, qb1, "64")
        CONSUME(2, 18, "30")  GLD2(bq[2][0], bq[2][1], qb0, qb1, "128")
        CONSUME(3, 19, "30")  GLD2(bq[3][0], bq[3][1], qb0, qb1, "192")
        CONSUME(4, 20, "30")  GLD2(bq[4][0], bq[4][1], qb0, qb1, "256")
        CONSUME(5, 21, "30")  GLD2(bq[5][0], bq[5][1], qb0, qb1, "320")
        CONSUME(6, 22, "30")  GLD2(bq[6][0], bq[6][1], qb0, qb1, "384")
        CONSUME(7, 23, "30")  GLD2(bq[7][0], bq[7][1], qb0, qb1, "448")
        CONSUME(8, 24, "30")  GLD2(bq[8][0], bq[8][1], qb0, qb1, "512")
        CONSUME(9, 25, "30")  GLD2(bq[9][0], bq[9][1], qb0, qb1, "576")
        CONSUME(10, 26, "30") GLD2(bq[10][0], bq[10][1], qb0, qb1, "640")
        CONSUME(11, 27, "30") GLD2(bq[11][0], bq[11][1], qb0, qb1, "704")
        CONSUME(12, 28, "30") GLD2(bq[12][0], bq[12][1], qb0, qb1, "768")
        CONSUME(13, 29, "30") GLD2(bq[13][0], bq[13][1], qb0, qb1, "832")
        CONSUME(14, 30, "30") GLD2(bq[14][0], bq[14][1], qb0, qb1, "896")
        CONSUME(15, 31, "30") GLD2(bq[15][0], bq[15][1], qb0, qb1, "960")
        CONSUME(0, 0, "30")   CONSUME(1, 1, "28")   CONSUME(2, 2, "26")  CONSUME(3, 3, "24")
        CONSUME(4, 4, "22")   CONSUME(5, 5, "20")   CONSUME(6, 6, "18")  CONSUME(7, 7, "16")
        CONSUME(8, 8, "14")   CONSUME(9, 9, "12")   CONSUME(10, 10, "10") CONSUME(11, 11, "8")
        CONSUME(12, 12, "6")  CONSUME(13, 13, "4")  CONSUME(14, 14, "2") CONSUME(15, 15, "0")
      }

      // ring back-pressure: slot t&7 overwrites h(t-8), consumed by layer l+1 at t-8
      if (t >= RING) {
        const unsigned int* pa = (l < 4) ? FLG(l + 1, t - RING) + (lane & 31)
                                         : FLG(5, t - RING) + (lane & 7);
        pollAll(pa);
      }

      // epilogue: gates -> c (regs), h -> ring via sc1 stores
      #pragma unroll
      for (int mf = 0; mf < 4; ++mf) {
        const int u = wgi * 16 + mf * 4 + l4;
        #pragma unroll
        for (int nf = 0; nf < 2; ++nf) {
          const int b = w * 32 + nf * 16 + l15;
          const float gi = acc[mf][nf][0] + b4m[mf].x;
          const float gf = acc[mf][nf][1] + b4m[mf].y;
          const float gg = acc[mf][nf][2] + b4m[mf].z;
          const float go = acc[mf][nf][3] + b4m[mf].w;
          const float cn = sigm(gf) * c_reg[mf][nf] + sigm(gi) * tanhfast(gg);
          c_reg[mf][nf] = cn;
          const unsigned int hv = f2bf(sigm(go) * tanhfast(cn));
          const unsigned short* ha = hout + (size_t)b * HID2 + u;
          asm volatile("global_store_short %0, %1, off sc0 sc1" :: "v"(ha), "v"(hv) : "memory");
        }
      }
      asm volatile("s_waitcnt vmcnt(0)" ::: "memory");
      __syncthreads();
      if (tid == 0) {
        const unsigned int* fa = FLG(l, t) + wgi;
        asm volatile("global_store_dword %0, %1, off sc0 sc1" :: "v"(fa), "v"(1u) : "memory");
      }
    }
  } else {
    // ---------------- projection blocks ----------------
    const int wgp = bid - 160;
    const int b0 = wgp * 16;
    for (int mf = 0; mf < 2; ++mf)
      for (int kit = 0; kit < 16; ++kit) {
        const s16x8 v = *reinterpret_cast<const s16x8*>(
            Woutb + (size_t)(w * 32 + mf * 16 + l15) * 512 + kit * 32 + l4 * 8);
        *reinterpret_cast<s16x8*>(smem + (((w * 2 + mf) * 16 + kit) << 10) + lane * 16) = v;
      }
    __syncthreads();
    float4 bo[2];
    #pragma unroll
    for (int mf = 0; mf < 2; ++mf)
      bo[mf] = *(const float4*)(boutp + w * 32 + mf * 16 + l4 * 4);

    s16x8 br[16];
    for (int t = 0; t < TT; ++t) {
      pollAll(FLG(4, t) + (lane & 31));
      const unsigned short* h4 = hring + (size_t)(4 * RING + (t & 7)) * NBH;
      const unsigned short* hb = h4 + (size_t)(b0 + l15) * HID2 + l4 * 8;
      GLD1(br[0], hb, "0")    GLD1(br[1], hb, "64")   GLD1(br[2], hb, "128")  GLD1(br[3], hb, "192")
      GLD1(br[4], hb, "256")  GLD1(br[5], hb, "320")  GLD1(br[6], hb, "384")  GLD1(br[7], hb, "448")
      GLD1(br[8], hb, "512")  GLD1(br[9], hb, "576")  GLD1(br[10], hb, "640") GLD1(br[11], hb, "704")
      GLD1(br[12], hb, "768") GLD1(br[13], hb, "832") GLD1(br[14], hb, "896") GLD1(br[15], hb, "960")
      f32x4 acc2[2] = {};
      #define PCON(Q, VM)                                                        \
        {                                                                        \
          BW1(br[Q], VM);                                                        \
          const s16x8 a0 = *reinterpret_cast<const s16x8*>(                      \
              smem + (((w * 2 + 0) * 16 + Q) << 10) + lane * 16);                \
          const s16x8 a1 = *reinterpret_cast<const s16x8*>(                      \
              smem + (((w * 2 + 1) * 16 + Q) << 10) + lane * 16);                \
          acc2[0] = MFM(a0, br[Q], acc2[0]);                                     \
          acc2[1] = MFM(a1, br[Q], acc2[1]);                                     \
        }
      PCON(0, "15")  PCON(1, "14")  PCON(2, "13")  PCON(3, "12")
      PCON(4, "11")  PCON(5, "10")  PCON(6, "9")   PCON(7, "8")
      PCON(8, "7")   PCON(9, "6")   PCON(10, "5")  PCON(11, "4")
      PCON(12, "3")  PCON(13, "2")  PCON(14, "1")  PCON(15, "0")
      #pragma unroll
      for (int mf = 0; mf < 2; ++mf) {
        const int d0 = w * 32 + mf * 16 + l4 * 4;
        float4 r;
        r.x = acc2[mf][0] + bo[mf].x;
        r.y = acc2[mf][1] + bo[mf].y;
        r.z = acc2[mf][2] + bo[mf].z;
        r.w = acc2[mf][3] + bo[mf].w;
        *(float4*)(outp + ((size_t)(b0 + l15) * TT + t) * 128 + d0) = r;
      }
      asm volatile("s_waitcnt vmcnt(0)" ::: "memory");
      __syncthreads();
      if (tid == 0) {
        const unsigned int* fa = FLG(5, t) + wgp;
        asm volatile("global_store_dword %0, %1, off sc0 sc1" :: "v"(fa), "v"(1u) : "memory");
      }
    }
  }
}

extern "C" void kernel_launch(void* const* d_in, const int* in_sizes, int n_in,
                              void* d_out, int out_size, void* d_ws, size_t ws_size,
                              hipStream_t stream) {
  (void)in_sizes; (void)n_in; (void)out_size; (void)ws_size;
  const float* x     = (const float*)d_in[0];
  const float* Wih1  = (const float*)d_in[1];
  const float* Whh1  = (const float*)d_in[2];
  const float* bih1  = (const float*)d_in[3];
  const float* bhh1  = (const float*)d_in[4];
  const float* Wih_r = (const float*)d_in[5];
  const float* Whh_r = (const float*)d_in[6];
  const float* bih_r = (const float*)d_in[7];
  const float* bhh_r = (const float*)d_in[8];
  const float* Wout  = (const float*)d_in[9];
  const float* boutp = (const float*)d_in[10];

  char* ws = (char*)d_ws;
  const size_t o_W0   = 0;
  const size_t o_W1   = o_W0 + 2048ull * 640 * 2;
  const size_t o_W2   = o_W1 + 2048ull * 1024 * 2;
  const size_t o_W3   = o_W2 + 2048ull * 1024 * 2;
  const size_t o_W4   = o_W3 + 2048ull * 1024 * 2;
  const size_t o_Wout = o_W4 + 2048ull * 1024 * 2;
  const size_t o_bias = o_Wout + 128ull * 512 * 2;
  const size_t o_ring = o_bias + 5ull * 2048 * 4;
  const size_t o_flag = o_ring + 5ull * RING * NBH * 2;
  const size_t o_end  = o_flag + 6ull * TT * 32 * 4;

  unsigned short* W0b  = (unsigned short*)(ws + o_W0);
  unsigned short* W1b  = (unsigned short*)(ws + o_W1);
  unsigned short* W2b  = (unsigned short*)(ws + o_W2);
  unsigned short* W3b  = (unsigned short*)(ws + o_W3);
  unsigned short* W4b  = (unsigned short*)(ws + o_W4);
  unsigned short* Wob  = (unsigned short*)(ws + o_Wout);
  float*          bias = (float*)(ws + o_bias);
  unsigned short* hrg  = (unsigned short*)(ws + o_ring);
  unsigned int*   flg  = (unsigned int*)(ws + o_flag);

  hipMemsetAsync(ws + o_ring, 0, o_end - o_ring, stream);

  convW<<<1024, 256, 0, stream>>>(Wih1, Whh1, bih1, bhh1, W0b, bias, 128, 512);
  for (int l = 1; l <= 4; ++l) {
    unsigned short* Wd = (l == 1) ? W1b : (l == 2) ? W2b : (l == 3) ? W3b : W4b;
    convW<<<1024, 256, 0, stream>>>(Wih_r + (size_t)(l - 1) * 2048 * 512,
                                    Whh_r + (size_t)(l - 1) * 2048 * 512,
                                    bih_r + (size_t)(l - 1) * 2048,
                                    bhh_r + (size_t)(l - 1) * 2048,
                                    Wd, bias + l * 2048, 512, 512);
  }
  convO<<<64, 256, 0, stream>>>(Wout, Wob);

  hipFuncSetAttribute((const void*)lstm_persist,
                      hipFuncAttributeMaxDynamicSharedMemorySize, 160 * 1024);

  lstm_persist<<<168, 256, 131072, stream>>>(x, W0b, W1b, W2b, W3b, W4b, Wob,
                                             bias, hrg, flg, boutp, (float*)d_out);
}

// Round 4
// 12469.128 us; speedup vs baseline: 2.9324x; 1.0831x over previous
//
#include <hip/hip_runtime.h>

// LSTM_65859028517106 — round 4: r3 + coalesced h stores (LDS transpose staging,
// one dwordx4 sc1 store per lane instead of 8 scattered 2B stores) + ring
// back-pressure poll overlapped with B-load latency.

typedef short s16x8 __attribute__((ext_vector_type(8)));
typedef float f32x4 __attribute__((ext_vector_type(4)));

#define NB   128
#define TT   1024
#define HID2 512
#define RING 8
#define NBH  (NB * HID2)
#define STAGE_OFF (128 * 1024)

__device__ __forceinline__ unsigned short f2bf(float f) {
  union { float f; unsigned int u; } c; c.f = f;
  return (unsigned short)((c.u + 0x7fffu + ((c.u >> 16) & 1u)) >> 16);
}
__device__ __forceinline__ float sigm(float x) { return 1.0f / (1.0f + __expf(-x)); }
__device__ __forceinline__ float tanhfast(float x) {
  x = fminf(fmaxf(x, -15.0f), 15.0f);
  const float e = __expf(2.0f * x);
  return (e - 1.0f) / (e + 1.0f);
}

__global__ void convW(const float* __restrict__ Wih, const float* __restrict__ Whh,
                      const float* __restrict__ bih, const float* __restrict__ bhh,
                      unsigned short* __restrict__ Wd, float* __restrict__ biasd,
                      const int Kih, const int Khh) {
  const int K = Kih + Khh;
  const int total = 2048 * K;
  for (int idx = blockIdx.x * blockDim.x + threadIdx.x; idx < total;
       idx += gridDim.x * blockDim.x) {
    const int rp = idx / K;
    const int cc = idx - rp * K;
    const int g = rp & 3, u = rp >> 2;
    const int ro = g * 512 + u;
    const float v = (cc < Kih) ? Wih[ro * Kih + cc] : Whh[ro * Khh + (cc - Kih)];
    Wd[idx] = f2bf(v);
    if (cc == 0) biasd[rp] = bih[ro] + bhh[ro];
  }
}

__global__ void convO(const float* __restrict__ Wout, unsigned short* __restrict__ Wd) {
  for (int idx = blockIdx.x * blockDim.x + threadIdx.x; idx < 128 * 512;
       idx += gridDim.x * blockDim.x)
    Wd[idx] = f2bf(Wout[idx]);
}

// --- sc0/sc1 (device-coherent) asm helpers ---
#define GLD2(D0, D1, B0, B1, OFF)                                         \
  asm volatile("global_load_dwordx4 %0, %2, off offset:" OFF " sc0 sc1\n\t" \
               "global_load_dwordx4 %1, %3, off offset:" OFF " sc0 sc1"   \
               : "=v"(D0), "=v"(D1) : "v"(B0), "v"(B1));
#define BWAIT(D0, D1, VM)                                                 \
  asm volatile("s_waitcnt vmcnt(" VM ")" : "+v"(D0), "+v"(D1)::"memory");
#define GLD1(D, B, OFF)                                                   \
  asm volatile("global_load_dwordx4 %0, %1, off offset:" OFF " sc0 sc1"   \
               : "=v"(D) : "v"(B));
#define BW1(D, VM)                                                        \
  asm volatile("s_waitcnt vmcnt(" VM ")" : "+v"(D)::"memory");

#define MFM(A, B, C) __builtin_amdgcn_mfma_f32_16x16x32_bf16(A, B, C, 0, 0, 0)
#define LDSA(MFi, AK) \
  (*reinterpret_cast<const s16x8*>(smem + (((MFi) * nkit + (AK)) << 10) + lane * 16))
#define CONSUME(SLOT, AK, VM)                                                   \
  {                                                                             \
    BWAIT(bq[SLOT][0], bq[SLOT][1], VM);                                        \
    const s16x8 af0 = LDSA(0, AK), af1 = LDSA(1, AK), af2 = LDSA(2, AK),        \
                af3 = LDSA(3, AK);                                              \
    acc[0][0] = MFM(af0, bq[SLOT][0], acc[0][0]);                               \
    acc[0][1] = MFM(af0, bq[SLOT][1], acc[0][1]);                               \
    acc[1][0] = MFM(af1, bq[SLOT][0], acc[1][0]);                               \
    acc[1][1] = MFM(af1, bq[SLOT][1], acc[1][1]);                               \
    acc[2][0] = MFM(af2, bq[SLOT][0], acc[2][0]);                               \
    acc[2][1] = MFM(af2, bq[SLOT][1], acc[2][1]);                               \
    acc[3][0] = MFM(af3, bq[SLOT][0], acc[3][0]);                               \
    acc[3][1] = MFM(af3, bq[SLOT][1], acc[3][1]);                               \
  }

__global__ __launch_bounds__(256, 1) void lstm_persist(
    const float* __restrict__ x,
    const unsigned short* __restrict__ W0, const unsigned short* __restrict__ W1,
    const unsigned short* __restrict__ W2, const unsigned short* __restrict__ W3,
    const unsigned short* __restrict__ W4,
    const unsigned short* __restrict__ Woutb,
    const float* __restrict__ bias,
    unsigned short* __restrict__ hring,   // [5][RING][128][512] bf16 (sc1 domain)
    unsigned int* __restrict__ flags,     // [6][TT][32] u32 (sc1 domain)
    const float* __restrict__ boutp,
    float* __restrict__ outp)
{
  extern __shared__ char smem[];
  const int tid = threadIdx.x;
  const int lane = tid & 63;
  const int w = tid >> 6;
  const int l15 = lane & 15;
  const int l4 = lane >> 4;
  const int bid = blockIdx.x;

  auto pollAll = [&](const unsigned int* pa) {
    for (;;) {
      unsigned int v;
      asm volatile("global_load_dword %0, %1, off sc0 sc1\n\ts_waitcnt vmcnt(0)"
                   : "=v"(v) : "v"(pa) : "memory");
      if (__all(v != 0)) break;
      __builtin_amdgcn_s_sleep(1);
    }
  };
  #define FLG(L, T) (flags + ((size_t)((L) * TT + (T)) << 5))

  if (bid < 160) {
    const int l = bid >> 5;
    const int wgi = bid & 31;
    const int K = (l == 0) ? 640 : 1024;
    const int nkit = K >> 5;
    const unsigned short* Wg = (l == 0) ? W0 : (l == 1) ? W1 : (l == 2) ? W2
                              : (l == 3) ? W3 : W4;
    const int row0 = wgi * 64;

    // one-time W fragment preload into LDS (normal cached loads)
    for (int mf = 0; mf < 4; ++mf)
      for (int kit = w; kit < nkit; kit += 4) {
        const s16x8 v = *reinterpret_cast<const s16x8*>(
            Wg + (size_t)(row0 + mf * 16 + l15) * K + kit * 32 + l4 * 8);
        *reinterpret_cast<s16x8*>(smem + ((mf * nkit + kit) << 10) + lane * 16) = v;
      }
    __syncthreads();

    float4 b4m[4];
    #pragma unroll
    for (int mf = 0; mf < 4; ++mf)
      b4m[mf] = *(const float4*)(bias + l * 2048 + row0 + mf * 16 + l4 * 4);

    float c_reg[4][2] = {};
    s16x8 bq[16][2];
    unsigned short* stage = (unsigned short*)(smem + STAGE_OFF);
    const int sb = w * 32 + (lane >> 1);   // store-back row this lane handles
    const int sh = lane & 1;               // which 8-unit half

    for (int t = 0; t < TT; ++t) {
      const unsigned short* hin =
          (l > 0) ? hring + (size_t)((l - 1) * RING + (t & 7)) * NBH : nullptr;
      const unsigned short* hown = hring + (size_t)(l * RING + ((t + 7) & 7)) * NBH;
      unsigned short* hout = hring + (size_t)(l * RING + (t & 7)) * NBH;

      f32x4 acc[4][2] = {};
      s16x8 xb[4][2];

      if (l == 0) {
        #pragma unroll
        for (int kx = 0; kx < 4; ++kx)
          #pragma unroll
          for (int nf = 0; nf < 2; ++nf) {
            const float* xs = x + ((size_t)(w * 32 + nf * 16 + l15) * TT + t) * 128
                              + kx * 32 + l4 * 8;
            const float4 v0 = *(const float4*)xs;
            const float4 v1 = *(const float4*)(xs + 4);
            union { s16x8 v; unsigned short a[8]; } pk;
            pk.a[0] = f2bf(v0.x); pk.a[1] = f2bf(v0.y); pk.a[2] = f2bf(v0.z); pk.a[3] = f2bf(v0.w);
            pk.a[4] = f2bf(v1.x); pk.a[5] = f2bf(v1.y); pk.a[6] = f2bf(v1.z); pk.a[7] = f2bf(v1.w);
            xb[kx][nf] = pk.v;
          }
      }

      // fused poll: lanes 0..31 = self(t-1), lanes 32..63 = prev(t)
      if (t > 0 || l > 0) {
        const unsigned int* pa;
        if (lane < 32)
          pa = (t > 0) ? FLG(l, t - 1) + lane : FLG(l - 1, t) + lane;
        else
          pa = (l > 0) ? FLG(l - 1, t) + (lane - 32) : FLG(l, t - 1) + (lane - 32);
        pollAll(pa);
      }

      const unsigned short* pb0 = hown + (size_t)(w * 32 + l15) * HID2 + l4 * 8;
      const unsigned short* pb1 = pb0 + 16 * HID2;

      if (l == 0) {
        GLD2(bq[0][0], bq[0][1], pb0, pb1, "0")    GLD2(bq[1][0], bq[1][1], pb0, pb1, "64")
        GLD2(bq[2][0], bq[2][1], pb0, pb1, "128")  GLD2(bq[3][0], bq[3][1], pb0, pb1, "192")
        GLD2(bq[4][0], bq[4][1], pb0, pb1, "256")  GLD2(bq[5][0], bq[5][1], pb0, pb1, "320")
        GLD2(bq[6][0], bq[6][1], pb0, pb1, "512")  GLD2(bq[7][0], bq[7][1], pb0, pb1, "448")
        GLD2(bq[8][0], bq[8][1], pb0, pb1, "384")  GLD2(bq[9][0], bq[9][1], pb0, pb1, "576")
        GLD2(bq[10][0], bq[10][1], pb0, pb1, "640") GLD2(bq[11][0], bq[11][1], pb0, pb1, "704")
        GLD2(bq[12][0], bq[12][1], pb0, pb1, "768") GLD2(bq[13][0], bq[13][1], pb0, pb1, "832")
        GLD2(bq[14][0], bq[14][1], pb0, pb1, "896") GLD2(bq[15][0], bq[15][1], pb0, pb1, "960")
        // x MFMAs cover part of the load latency
        #pragma unroll
        for (int kx = 0; kx < 4; ++kx) {
          const s16x8 a0 = LDSA(0, kx), a1 = LDSA(1, kx), a2 = LDSA(2, kx), a3 = LDSA(3, kx);
          acc[0][0] = MFM(a0, xb[kx][0], acc[0][0]); acc[0][1] = MFM(a0, xb[kx][1], acc[0][1]);
          acc[1][0] = MFM(a1, xb[kx][0], acc[1][0]); acc[1][1] = MFM(a1, xb[kx][1], acc[1][1]);
          acc[2][0] = MFM(a2, xb[kx][0], acc[2][0]); acc[2][1] = MFM(a2, xb[kx][1], acc[2][1]);
          acc[3][0] = MFM(a3, xb[kx][0], acc[3][0]); acc[3][1] = MFM(a3, xb[kx][1], acc[3][1]);
        }
        // ring back-pressure poll, overlapped with B-load latency
        if (t >= RING) pollAll(FLG(l + 1, t - RING) + (lane & 31));
        CONSUME(0, 4, "30")   CONSUME(1, 5, "28")   CONSUME(2, 6, "26")   CONSUME(3, 7, "24")
        CONSUME(4, 8, "22")   CONSUME(5, 9, "20")   CONSUME(6, 10, "18")  CONSUME(7, 11, "16")
        CONSUME(8, 12, "14")  CONSUME(9, 13, "12")  CONSUME(10, 14, "10") CONSUME(11, 15, "8")
        CONSUME(12, 16, "6")  CONSUME(13, 17, "4")  CONSUME(14, 18, "2")  CONSUME(15, 19, "0")
      } else {
        const unsigned short* qb0 = hin + (size_t)(w * 32 + l15) * HID2 + l4 * 8;
        const unsigned short* qb1 = qb0 + 16 * HID2;
        GLD2(bq[0][0], bq[0][1], pb0, pb1, "0")    GLD2(bq[1][0], bq[1][1], pb0, pb1, "64")
        GLD2(bq[2][0], bq[2][1], pb0, pb1, "128")  GLD2(bq[3][0], bq[3][1], pb0, pb1, "192")
        GLD2(bq[4][0], bq[4][1], pb0, pb1, "256")  GLD2(bq[5][0], bq[5][1], pb0, pb1, "320")
        GLD2(bq[6][0], bq[6][1], pb0, pb1, "384")  GLD2(bq[7][0], bq[7][1], pb0, pb1, "448")
        GLD2(bq[8][0], bq[8][1], pb0, pb1, "512")  GLD2(bq[9][0], bq[9][1], pb0, pb1, "576")
        GLD2(bq[10][0], bq[10][1], pb0, pb1, "640") GLD2(bq[11][0], bq[11][1], pb0, pb1, "704")
        GLD2(bq[12][0], bq[12][1], pb0, pb1, "768") GLD2(bq[13][0], bq[13][1], pb0, pb1, "832")
        GLD2(bq[14][0], bq[14][1], pb0, pb1, "896") GLD2(bq[15][0], bq[15][1], pb0, pb1, "960")
        // ring back-pressure poll, overlapped with B-load latency
        if (t >= RING) {
          const unsigned int* pa = (l < 4) ? FLG(l + 1, t - RING) + (lane & 31)
                                           : FLG(5, t - RING) + (lane & 7);
          pollAll(pa);
        }
        CONSUME(0, 16, "30")  GLD2(bq[0][0], bq[0][1], qb0, qb1, "0")
        CONSUME(1, 17, "30")  GLD2(bq[1][0], bq[1][1], qb0, qb1, "64")
        CONSUME(2, 18, "30")  GLD2(bq[2][0], bq[2][1], qb0, qb1, "128")
        CONSUME(3, 19, "30")  GLD2(bq[3][0], bq[3][1], qb0, qb1, "192")
        CONSUME(4, 20, "30")  GLD2(bq[4][0], bq[4][1], qb0, qb1, "256")
        CONSUME(5, 21, "30")  GLD2(bq[5][0], bq[5][1], qb0, qb1, "320")
        CONSUME(6, 22, "30")  GLD2(bq[6][0], bq[6][1], qb0, qb1, "384")
        CONSUME(7, 23, "30")  GLD2(bq[7][0], bq[7][1], qb0, qb1, "448")
        CONSUME(8, 24, "30")  GLD2(bq[8][0], bq[8][1], qb0, qb1, "512")
        CONSUME(9, 25, "30")  GLD2(bq[9][0], bq[9][1], qb0, qb1, "576")
        CONSUME(10, 26, "30") GLD2(bq[10][0], bq[10][1], qb0, qb1, "640")
        CONSUME(11, 27, "30") GLD2(bq[11][0], bq[11][1], qb0, qb1, "704")
        CONSUME(12, 28, "30") GLD2(bq[12][0], bq[12][1], qb0, qb1, "768")
        CONSUME(13, 29, "30") GLD2(bq[13][0], bq[13][1], qb0, qb1, "832")
        CONSUME(14, 30, "30") GLD2(bq[14][0], bq[14][1], qb0, qb1, "896")
        CONSUME(15, 31, "30") GLD2(bq[15][0], bq[15][1], qb0, qb1, "960")
        CONSUME(0, 0, "30")   CONSUME(1, 1, "28")   CONSUME(2, 2, "26")  CONSUME(3, 3, "24")
        CONSUME(4, 4, "22")   CONSUME(5, 5, "20")   CONSUME(6, 6, "18")  CONSUME(7, 7, "16")
        CONSUME(8, 8, "14")   CONSUME(9, 9, "12")   CONSUME(10, 10, "10") CONSUME(11, 11, "8")
        CONSUME(12, 12, "6")  CONSUME(13, 13, "4")  CONSUME(14, 14, "2") CONSUME(15, 15, "0")
      }

      // ---- epilogue: gates -> c (regs); h -> LDS transpose stage -> one
      // coalesced dwordx4 sc1 store per lane ----
      #pragma unroll
      for (int mf = 0; mf < 4; ++mf) {
        #pragma unroll
        for (int nf = 0; nf < 2; ++nf) {
          const float gi = acc[mf][nf][0] + b4m[mf].x;
          const float gf = acc[mf][nf][1] + b4m[mf].y;
          const float gg = acc[mf][nf][2] + b4m[mf].z;
          const float go = acc[mf][nf][3] + b4m[mf].w;
          const float cn = sigm(gf) * c_reg[mf][nf] + sigm(gi) * tanhfast(gg);
          c_reg[mf][nf] = cn;
          // stage[b_local][u_local], b_local = w*32+nf*16+l15, u_local = mf*4+l4
          stage[(w * 32 + nf * 16 + l15) * 16 + mf * 4 + l4] =
              f2bf(sigm(go) * tanhfast(cn));
        }
      }
      asm volatile("s_waitcnt lgkmcnt(0)" ::: "memory");
      __builtin_amdgcn_sched_barrier(0);
      {
        const s16x8 hvv = *reinterpret_cast<const s16x8*>(
            (const char*)stage + sb * 32 + sh * 16);
        const unsigned short* ha = hout + (size_t)sb * HID2 + wgi * 16 + sh * 8;
        asm volatile("global_store_dwordx4 %0, %1, off sc0 sc1"
                     :: "v"(ha), "v"(hvv) : "memory");
      }
      asm volatile("s_waitcnt vmcnt(0)" ::: "memory");
      __syncthreads();
      if (tid == 0) {
        const unsigned int* fa = FLG(l, t) + wgi;
        asm volatile("global_store_dword %0, %1, off sc0 sc1" :: "v"(fa), "v"(1u) : "memory");
      }
    }
  } else {
    // ---------------- projection blocks ----------------
    const int wgp = bid - 160;
    const int b0 = wgp * 16;
    for (int mf = 0; mf < 2; ++mf)
      for (int kit = 0; kit < 16; ++kit) {
        const s16x8 v = *reinterpret_cast<const s16x8*>(
            Woutb + (size_t)(w * 32 + mf * 16 + l15) * 512 + kit * 32 + l4 * 8);
        *reinterpret_cast<s16x8*>(smem + (((w * 2 + mf) * 16 + kit) << 10) + lane * 16) = v;
      }
    __syncthreads();
    float4 bo[2];
    #pragma unroll
    for (int mf = 0; mf < 2; ++mf)
      bo[mf] = *(const float4*)(boutp + w * 32 + mf * 16 + l4 * 4);

    s16x8 br[16];
    for (int t = 0; t < TT; ++t) {
      pollAll(FLG(4, t) + (lane & 31));
      const unsigned short* h4 = hring + (size_t)(4 * RING + (t & 7)) * NBH;
      const unsigned short* hb = h4 + (size_t)(b0 + l15) * HID2 + l4 * 8;
      GLD1(br[0], hb, "0")    GLD1(br[1], hb, "64")   GLD1(br[2], hb, "128")  GLD1(br[3], hb, "192")
      GLD1(br[4], hb, "256")  GLD1(br[5], hb, "320")  GLD1(br[6], hb, "384")  GLD1(br[7], hb, "448")
      GLD1(br[8], hb, "512")  GLD1(br[9], hb, "576")  GLD1(br[10], hb, "640") GLD1(br[11], hb, "704")
      GLD1(br[12], hb, "768") GLD1(br[13], hb, "832") GLD1(br[14], hb, "896") GLD1(br[15], hb, "960")
      f32x4 acc2[2] = {};
      #define PCON(Q, VM)                                                        \
        {                                                                        \
          BW1(br[Q], VM);                                                        \
          const s16x8 a0 = *reinterpret_cast<const s16x8*>(                      \
              smem + (((w * 2 + 0) * 16 + Q) << 10) + lane * 16);                \
          const s16x8 a1 = *reinterpret_cast<const s16x8*>(                      \
              smem + (((w * 2 + 1) * 16 + Q) << 10) + lane * 16);                \
          acc2[0] = MFM(a0, br[Q], acc2[0]);                                     \
          acc2[1] = MFM(a1, br[Q], acc2[1]);                                     \
        }
      PCON(0, "15")  PCON(1, "14")  PCON(2, "13")  PCON(3, "12")
      PCON(4, "11")  PCON(5, "10")  PCON(6, "9")   PCON(7, "8")
      PCON(8, "7")   PCON(9, "6")   PCON(10, "5")  PCON(11, "4")
      PCON(12, "3")  PCON(13, "2")  PCON(14, "1")  PCON(15, "0")
      #pragma unroll
      for (int mf = 0; mf < 2; ++mf) {
        const int d0 = w * 32 + mf * 16 + l4 * 4;
        float4 r;
        r.x = acc2[mf][0] + bo[mf].x;
        r.y = acc2[mf][1] + bo[mf].y;
        r.z = acc2[mf][2] + bo[mf].z;
        r.w = acc2[mf][3] + bo[mf].w;
        *(float4*)(outp + ((size_t)(b0 + l15) * TT + t) * 128 + d0) = r;
      }
      asm volatile("s_waitcnt vmcnt(0)" ::: "memory");
      __syncthreads();
      if (tid == 0) {
        const unsigned int* fa = FLG(5, t) + wgp;
        asm volatile("global_store_dword %0, %1, off sc0 sc1" :: "v"(fa), "v"(1u) : "memory");
      }
    }
  }
}

extern "C" void kernel_launch(void* const* d_in, const int* in_sizes, int n_in,
                              void* d_out, int out_size, void* d_ws, size_t ws_size,
                              hipStream_t stream) {
  (void)in_sizes; (void)n_in; (void)out_size; (void)ws_size;
  const float* x     = (const float*)d_in[0];
  const float* Wih1  = (const float*)d_in[1];
  const float* Whh1  = (const float*)d_in[2];
  const float* bih1  = (const float*)d_in[3];
  const float* bhh1  = (const float*)d_in[4];
  const float* Wih_r = (const float*)d_in[5];
  const float* Whh_r = (const float*)d_in[6];
  const float* bih_r = (const float*)d_in[7];
  const float* bhh_r = (const float*)d_in[8];
  const float* Wout  = (const float*)d_in[9];
  const float* boutp = (const float*)d_in[10];

  char* ws = (char*)d_ws;
  const size_t o_W0   = 0;
  const size_t o_W1   = o_W0 + 2048ull * 640 * 2;
  const size_t o_W2   = o_W1 + 2048ull * 1024 * 2;
  const size_t o_W3   = o_W2 + 2048ull * 1024 * 2;
  const size_t o_W4   = o_W3 + 2048ull * 1024 * 2;
  const size_t o_Wout = o_W4 + 2048ull * 1024 * 2;
  const size_t o_bias = o_Wout + 128ull * 512 * 2;
  const size_t o_ring = o_bias + 5ull * 2048 * 4;
  const size_t o_flag = o_ring + 5ull * RING * NBH * 2;
  const size_t o_end  = o_flag + 6ull * TT * 32 * 4;

  unsigned short* W0b  = (unsigned short*)(ws + o_W0);
  unsigned short* W1b  = (unsigned short*)(ws + o_W1);
  unsigned short* W2b  = (unsigned short*)(ws + o_W2);
  unsigned short* W3b  = (unsigned short*)(ws + o_W3);
  unsigned short* W4b  = (unsigned short*)(ws + o_W4);
  unsigned short* Wob  = (unsigned short*)(ws + o_Wout);
  float*          bias = (float*)(ws + o_bias);
  unsigned short* hrg  = (unsigned short*)(ws + o_ring);
  unsigned int*   flg  = (unsigned int*)(ws + o_flag);

  hipMemsetAsync(ws + o_ring, 0, o_end - o_ring, stream);

  convW<<<1024, 256, 0, stream>>>(Wih1, Whh1, bih1, bhh1, W0b, bias, 128, 512);
  for (int l = 1; l <= 4; ++l) {
    unsigned short* Wd = (l == 1) ? W1b : (l == 2) ? W2b : (l == 3) ? W3b : W4b;
    convW<<<1024, 256, 0, stream>>>(Wih_r + (size_t)(l - 1) * 2048 * 512,
                                    Whh_r + (size_t)(l - 1) * 2048 * 512,
                                    bih_r + (size_t)(l - 1) * 2048,
                                    bhh_r + (size_t)(l - 1) * 2048,
                                    Wd, bias + l * 2048, 512, 512);
  }
  convO<<<64, 256, 0, stream>>>(Wout, Wob);

  hipFuncSetAttribute((const void*)lstm_persist,
                      hipFuncAttributeMaxDynamicSharedMemorySize, 160 * 1024);

  lstm_persist<<<168, 256, 135168, stream>>>(x, W0b, W1b, W2b, W3b, W4b, Wob,
                                             bias, hrg, flg, boutp, (float*)d_out);
}